// Round 4
// baseline (2057.540 us; speedup 1.0000x reference)
//
#include <hip/hip_runtime.h>
#include <hip/hip_bf16.h>

#define N_FEAT 128
#define DIM 64

// ---------------- graph prep ----------------

__global__ void hist_kernel(const int* __restrict__ dst, int E, int* __restrict__ cnt) {
    int e = blockIdx.x * blockDim.x + threadIdx.x;
    if (e < E) atomicAdd(&cnt[dst[e]], 1);
}

__global__ void dis_kernel(const int* __restrict__ cnt, float* __restrict__ dis, int N) {
    int i = blockIdx.x * blockDim.x + threadIdx.x;
    if (i < N) dis[i] = rsqrtf((float)cnt[i] + 1.0f);
}

// pass A: per-block (1024 elems) inclusive scan, block totals out
__global__ void scanA_kernel(const int* __restrict__ cnt, int N,
                             int* __restrict__ tmp, int* __restrict__ blk) {
    __shared__ int ts[256];
    int t = threadIdx.x;
    int base = blockIdx.x * 1024 + t * 4;
    int v[4];
    int s = 0;
#pragma unroll
    for (int j = 0; j < 4; j++) {
        int i = base + j;
        v[j] = (i < N) ? cnt[i] : 0;
        s += v[j];
    }
    ts[t] = s;
    __syncthreads();
    for (int off = 1; off < 256; off <<= 1) {
        int x = (t >= off) ? ts[t - off] : 0;
        __syncthreads();
        ts[t] += x;
        __syncthreads();
    }
    int run = ts[t] - s;
#pragma unroll
    for (int j = 0; j < 4; j++) {
        run += v[j];
        int i = base + j;
        if (i < N) tmp[i] = run;
    }
    if (t == 255) blk[blockIdx.x] = ts[255];
}

// pass B: exclusive scan of block totals (single block)
__global__ void scanB_kernel(int* __restrict__ blk, int nb) {
    __shared__ int ts[128];
    int t = threadIdx.x;
    int v = (t < nb) ? blk[t] : 0;
    ts[t] = v;
    __syncthreads();
    for (int off = 1; off < 128; off <<= 1) {
        int x = (t >= off) ? ts[t - off] : 0;
        __syncthreads();
        ts[t] += x;
        __syncthreads();
    }
    if (t < nb) blk[t] = ts[t] - v;
}

// pass C: final exclusive row_ptr + cursor copy
__global__ void scanC_kernel(const int* __restrict__ tmp, const int* __restrict__ blk,
                             int N, int E, int* __restrict__ rowp, int* __restrict__ cur) {
    int i = blockIdx.x * blockDim.x + threadIdx.x;
    if (i < N) {
        int b = i >> 10;
        int local = i & 1023;
        int excl = blk[b] + (local ? tmp[i - 1] : 0);
        rowp[i] = excl;
        cur[i] = excl;
    }
    if (i == 0) rowp[N] = E;
}

__global__ void fill_kernel(const int* __restrict__ src, const int* __restrict__ dst, int E,
                            const float* __restrict__ dis, int* __restrict__ cur,
                            int* __restrict__ col, float* __restrict__ wts) {
    int e = blockIdx.x * blockDim.x + threadIdx.x;
    if (e < E) {
        int s = src[e], d = dst[e];
        int pos = atomicAdd(&cur[d], 1);
        col[pos] = s;
        wts[pos] = dis[s] * dis[d];
    }
}

// ---------------- GEMM: C[M,64] = f(A[M,K]) @ W[K,64] ----------------
// f = optional per-input-channel affine (fused BN from previous layer)
// optional bias/relu/stats epilogue (for MLP layers)

template<int K, bool AFFINE, bool BIAS, bool RELU, bool STATS>
__global__ __launch_bounds__(256) void gemm_kernel(
    const float* __restrict__ A, const float* __restrict__ W,
    const float* __restrict__ scale, const float* __restrict__ shift,
    const float* __restrict__ bias, float* __restrict__ C,
    float* __restrict__ stats, int M)
{
    __shared__ float As[64][K + 1];
    __shared__ float Ws[K][64];
    __shared__ float bs[64], bq[64];
    int t = threadIdx.x;
    int row0 = blockIdx.x * 64;

    // load W (K x 64), row-major, coalesced
    for (int q = t; q < K * 16; q += 256) {
        int k = q >> 4, c4 = (q & 15) << 2;
        float4 w = *reinterpret_cast<const float4*>(&W[k * 64 + c4]);
        *reinterpret_cast<float4*>(&Ws[k][c4]) = w;
    }
    // load A tile (64 rows x K), apply affine on load
    for (int q = t; q < 64 * (K / 4); q += 256) {
        int r = q / (K / 4);
        int k4 = (q % (K / 4)) * 4;
        int row = row0 + r;
        float4 a;
        if (row < M) {
            a = *reinterpret_cast<const float4*>(&A[(size_t)row * K + k4]);
            if (AFFINE) {
                a.x = a.x * scale[k4]     + shift[k4];
                a.y = a.y * scale[k4 + 1] + shift[k4 + 1];
                a.z = a.z * scale[k4 + 2] + shift[k4 + 2];
                a.w = a.w * scale[k4 + 3] + shift[k4 + 3];
            }
        } else {
            a = make_float4(0.f, 0.f, 0.f, 0.f);
        }
        As[r][k4] = a.x; As[r][k4 + 1] = a.y; As[r][k4 + 2] = a.z; As[r][k4 + 3] = a.w;
    }
    __syncthreads();

    int ty = t >> 4, tx = t & 15;
    int r0 = ty * 4, c0 = tx * 4;
    float acc[4][4] = {};
#pragma unroll 8
    for (int k = 0; k < K; k++) {
        float a0 = As[r0][k], a1 = As[r0 + 1][k], a2 = As[r0 + 2][k], a3 = As[r0 + 3][k];
        float4 w = *reinterpret_cast<const float4*>(&Ws[k][c0]);
        acc[0][0] += a0 * w.x; acc[0][1] += a0 * w.y; acc[0][2] += a0 * w.z; acc[0][3] += a0 * w.w;
        acc[1][0] += a1 * w.x; acc[1][1] += a1 * w.y; acc[1][2] += a1 * w.z; acc[1][3] += a1 * w.w;
        acc[2][0] += a2 * w.x; acc[2][1] += a2 * w.y; acc[2][2] += a2 * w.z; acc[2][3] += a2 * w.w;
        acc[3][0] += a3 * w.x; acc[3][1] += a3 * w.y; acc[3][2] += a3 * w.z; acc[3][3] += a3 * w.w;
    }

    if (STATS) {
        if (t < 64) { bs[t] = 0.f; bq[t] = 0.f; }
        __syncthreads();
    }
    float ssum[4] = {0.f, 0.f, 0.f, 0.f}, ssq[4] = {0.f, 0.f, 0.f, 0.f};
#pragma unroll
    for (int i = 0; i < 4; i++) {
        int row = row0 + r0 + i;
        if (row < M) {
            float4 v;
            float* vp = &v.x;
#pragma unroll
            for (int j = 0; j < 4; j++) {
                float x = acc[i][j];
                if (BIAS) x += bias[c0 + j];
                if (RELU) x = fmaxf(x, 0.f);
                vp[j] = x;
                if (STATS) { ssum[j] += x; ssq[j] += x * x; }
            }
            *reinterpret_cast<float4*>(&C[(size_t)row * 64 + c0]) = v;
        }
    }
    if (STATS) {
#pragma unroll
        for (int j = 0; j < 4; j++) {
            atomicAdd(&bs[c0 + j], ssum[j]);
            atomicAdd(&bq[c0 + j], ssq[j]);
        }
        __syncthreads();
        if (t < 64) {
            atomicAdd(&stats[t], bs[t]);
            atomicAdd(&stats[64 + t], bq[t]);
        }
    }
}

// ---------------- edge aggregation (one wave = one node, lane = channel) ----------------

template<bool RELU>
__global__ __launch_bounds__(256) void agg_kernel(
    const float* __restrict__ H, const int* __restrict__ rowp,
    const int* __restrict__ col, const float* __restrict__ wts,
    const float* __restrict__ dis, const float* __restrict__ bias,
    float* __restrict__ Hout, float* __restrict__ stats, int N)
{
    __shared__ float bs[64], bq[64];
    int t = threadIdx.x;
    int lane = t & 63;
    int base = (blockIdx.x * 4 + (t >> 6)) * 8;
    float b = bias[lane];
    float ssum = 0.f, ssq = 0.f;
    for (int u = 0; u < 8; u++) {
        int n = base + u;
        if (n >= N) break;
        int e0 = rowp[n], e1 = rowp[n + 1];
        float acc = 0.f;
        for (int e = e0; e < e1; e++) {
            int s = col[e];
            float w = wts[e];
            acc += H[(size_t)s * 64 + lane] * w;
        }
        float dn = dis[n];
        acc += H[(size_t)n * 64 + lane] * (dn * dn);
        acc += b;
        if (RELU) acc = fmaxf(acc, 0.f);
        Hout[(size_t)n * 64 + lane] = acc;
        ssum += acc;
        ssq += acc * acc;
    }
    if (t < 64) { bs[t] = 0.f; bq[t] = 0.f; }
    __syncthreads();
    atomicAdd(&bs[lane], ssum);
    atomicAdd(&bq[lane], ssq);
    __syncthreads();
    if (t < 64) {
        atomicAdd(&stats[t], bs[t]);
        atomicAdd(&stats[64 + t], bq[t]);
    }
}

// ---------------- BN prep: stats -> (scale, shift) ----------------

__global__ void bnprep_kernel(const float* __restrict__ stats, const float* __restrict__ g,
                              const float* __restrict__ b, float* __restrict__ ss, float cntInv) {
    int c = threadIdx.x;
    float mean = stats[c] * cntInv;
    float var = stats[64 + c] * cntInv - mean * mean;
    float sc = g[c] * rsqrtf(var + 1e-5f);
    ss[c] = sc;
    ss[64 + c] = b[c] - mean * sc;
}

// ---------------- pooling (batch sorted -> run-length accumulate) ----------------

__global__ __launch_bounds__(256) void pool_kernel(
    const float* __restrict__ H, const int* __restrict__ batch,
    const float* __restrict__ ss, float* __restrict__ P, int N)
{
    int t = threadIdx.x;
    int lane = t & 63;
    int base = (blockIdx.x * 4 + (t >> 6)) * 8;
    float sc = ss[lane], sh = ss[64 + lane];
    float acc = 0.f;
    int gprev = -1;
    for (int u = 0; u < 8; u++) {
        int n = base + u;
        if (n >= N) break;
        int g = batch[n];
        if (g != gprev) {
            if (gprev >= 0) atomicAdd(&P[(size_t)gprev * 64 + lane], acc);
            acc = 0.f;
            gprev = g;
        }
        acc += H[(size_t)n * 64 + lane] * sc + sh;
    }
    if (gprev >= 0) atomicAdd(&P[(size_t)gprev * 64 + lane], acc);
}

// ---------------- output head ----------------

__global__ __launch_bounds__(256) void final_kernel(
    const float* __restrict__ P, const float* __restrict__ ss,
    const float* __restrict__ outw, const float* __restrict__ outb,
    float* __restrict__ out, int G)
{
    int t = threadIdx.x;
    int lane = t & 63;
    int g = blockIdx.x * 4 + (t >> 6);
    if (g >= G) return;
    float v = (P[(size_t)g * 64 + lane] * ss[lane] + ss[64 + lane]) * outw[lane];
#pragma unroll
    for (int off = 32; off >= 1; off >>= 1) v += __shfl_xor(v, off, 64);
    if (lane == 0) out[g] = v + outb[0];
}

// ---------------- launch ----------------

extern "C" void kernel_launch(void* const* d_in, const int* in_sizes, int n_in,
                              void* d_out, int out_size, void* d_ws, size_t ws_size,
                              hipStream_t stream)
{
    const float* x      = (const float*)d_in[0];
    const int*   ei     = (const int*)d_in[1];
    const int*   batch  = (const int*)d_in[2];
    const float* w1     = (const float*)d_in[3];
    const float* b1     = (const float*)d_in[4];
    const float* bn1_g  = (const float*)d_in[5];
    const float* bn1_b  = (const float*)d_in[6];
    const float* conv_w = (const float*)d_in[7];
    const float* conv_b = (const float*)d_in[8];
    const float* bnc_g  = (const float*)d_in[9];
    const float* bnc_b  = (const float*)d_in[10];
    const float* mlp_w  = (const float*)d_in[11];
    const float* mlp_b  = (const float*)d_in[12];
    const float* bnm_g  = (const float*)d_in[13];
    const float* bnm_b  = (const float*)d_in[14];
    const float* out_w  = (const float*)d_in[15];
    const float* out_b  = (const float*)d_in[16];
    float* out = (float*)d_out;

    const int N = in_sizes[0] / N_FEAT;   // 100000 nodes
    const int E = in_sizes[1] / 2;        // 3.2M edges
    const int G = out_size;               // 4096 graphs
    const int* esrc = ei;
    const int* edst = ei + E;

    char* ws = (char*)d_ws;
    size_t off = 0;
    auto alloc = [&](size_t bytes) {
        size_t cur = off;
        off += (bytes + 255) & ~(size_t)255;
        return (void*)(ws + cur);
    };

    int*   deg   = (int*)alloc((size_t)N * 4);
    float* dis   = (float*)alloc((size_t)N * 4);
    int*   rtmp  = (int*)alloc((size_t)N * 4);
    int*   rowp  = (int*)alloc((size_t)(N + 1) * 4);
    int*   cur   = (int*)alloc((size_t)N * 4);
    int*   blk   = (int*)alloc(256 * 4);
    int*   col   = (int*)alloc((size_t)E * 4);
    float* wts   = (float*)alloc((size_t)E * 4);
    float* bufA  = (float*)alloc((size_t)(N + 64) * 64 * 4);
    float* bufB  = (float*)alloc((size_t)(N + 64) * 64 * 4);
    float* stats = (float*)alloc(7 * 128 * 4);
    float* ssbuf = (float*)alloc(7 * 128 * 4);
    float* P     = (float*)alloc((size_t)G * 64 * 4);
    float* pA    = (float*)alloc((size_t)G * 64 * 4);
    float* pB    = (float*)alloc((size_t)G * 64 * 4);

    hipMemsetAsync(deg, 0, (size_t)N * 4, stream);
    hipMemsetAsync(stats, 0, 7 * 128 * 4, stream);
    hipMemsetAsync(P, 0, (size_t)G * 64 * 4, stream);

    // graph prep
    hist_kernel<<<(E + 255) / 256, 256, 0, stream>>>(edst, E, deg);
    dis_kernel<<<(N + 255) / 256, 256, 0, stream>>>(deg, dis, N);
    int nchunk = (N + 1023) / 1024;
    scanA_kernel<<<nchunk, 256, 0, stream>>>(deg, N, rtmp, blk);
    scanB_kernel<<<1, 128, 0, stream>>>(blk, nchunk);
    scanC_kernel<<<(N + 255) / 256, 256, 0, stream>>>(rtmp, blk, N, E, rowp, cur);
    fill_kernel<<<(E + 255) / 256, 256, 0, stream>>>(esrc, edst, E, dis, cur, col, wts);

    int gemmN_grid = (N + 63) / 64;
    int aggN_grid = (N + 31) / 32;

    // layer 1: x @ w1 -> agg (+b1, relu, stats0)
    gemm_kernel<128, false, false, false, false><<<gemmN_grid, 256, 0, stream>>>(
        x, w1, nullptr, nullptr, nullptr, bufA, nullptr, N);
    agg_kernel<true><<<aggN_grid, 256, 0, stream>>>(
        bufA, rowp, col, wts, dis, b1, bufB, stats, N);
    bnprep_kernel<<<1, 64, 0, stream>>>(stats, bn1_g, bn1_b, ssbuf, 1.0f / N);

    // conv layers
    for (int i = 0; i < 3; i++) {
        const float* W  = conv_w + (size_t)i * 64 * 64;
        const float* bb = conv_b + (size_t)i * 64;
        float* st     = stats + (size_t)(1 + i) * 128;
        float* ss_in  = ssbuf + (size_t)i * 128;
        float* ss_out = ssbuf + (size_t)(1 + i) * 128;
        gemm_kernel<64, true, false, false, false><<<gemmN_grid, 256, 0, stream>>>(
            bufB, W, ss_in, ss_in + 64, nullptr, bufA, nullptr, N);
        agg_kernel<false><<<aggN_grid, 256, 0, stream>>>(
            bufA, rowp, col, wts, dis, bb, bufB, st, N);
        bnprep_kernel<<<1, 64, 0, stream>>>(st, bnc_g + (size_t)i * 64, bnc_b + (size_t)i * 64,
                                            ss_out, 1.0f / N);
    }

    // pooling (applies conv3 BN)
    pool_kernel<<<aggN_grid, 256, 0, stream>>>(bufB, batch, ssbuf + 3 * 128, P, N);

    // MLP
    int gemmG_grid = (G + 63) / 64;
    gemm_kernel<64, false, true, true, true><<<gemmG_grid, 256, 0, stream>>>(
        P, mlp_w, nullptr, nullptr, mlp_b, pA, stats + 4 * 128, G);
    bnprep_kernel<<<1, 64, 0, stream>>>(stats + 4 * 128, bnm_g, bnm_b, ssbuf + 4 * 128, 1.0f / G);

    gemm_kernel<64, true, true, true, true><<<gemmG_grid, 256, 0, stream>>>(
        pA, mlp_w + 64 * 64, ssbuf + 4 * 128, ssbuf + 4 * 128 + 64,
        mlp_b + 64, pB, stats + 5 * 128, G);
    bnprep_kernel<<<1, 64, 0, stream>>>(stats + 5 * 128, bnm_g + 64, bnm_b + 64, ssbuf + 5 * 128, 1.0f / G);

    gemm_kernel<64, true, true, true, true><<<gemmG_grid, 256, 0, stream>>>(
        pB, mlp_w + 2 * 64 * 64, ssbuf + 5 * 128, ssbuf + 5 * 128 + 64,
        mlp_b + 2 * 64, pA, stats + 6 * 128, G);
    bnprep_kernel<<<1, 64, 0, stream>>>(stats + 6 * 128, bnm_g + 2 * 64, bnm_b + 2 * 64, ssbuf + 6 * 128, 1.0f / G);

    final_kernel<<<(G + 3) / 4, 256, 0, stream>>>(pA, ssbuf + 6 * 128, out_w, out_b, out, G);
}

// Round 5
// 1218.411 us; speedup vs baseline: 1.6887x; 1.6887x over previous
//
#include <hip/hip_runtime.h>
#include <hip/hip_bf16.h>

#define N_FEAT 128
#define DIM 64

// ---------------- graph prep ----------------

__global__ void hist_kernel(const int* __restrict__ dst, int E, int* __restrict__ cnt) {
    int e = blockIdx.x * blockDim.x + threadIdx.x;
    if (e < E) atomicAdd(&cnt[dst[e]], 1);
}

__global__ void dis_kernel(const int* __restrict__ cnt, float* __restrict__ dis, int N) {
    int i = blockIdx.x * blockDim.x + threadIdx.x;
    if (i < N) dis[i] = rsqrtf((float)cnt[i] + 1.0f);
}

// pass A: per-block (1024 elems) inclusive scan, block totals out
__global__ void scanA_kernel(const int* __restrict__ cnt, int N,
                             int* __restrict__ tmp, int* __restrict__ blk) {
    __shared__ int ts[256];
    int t = threadIdx.x;
    int base = blockIdx.x * 1024 + t * 4;
    int v[4];
    int s = 0;
#pragma unroll
    for (int j = 0; j < 4; j++) {
        int i = base + j;
        v[j] = (i < N) ? cnt[i] : 0;
        s += v[j];
    }
    ts[t] = s;
    __syncthreads();
    for (int off = 1; off < 256; off <<= 1) {
        int x = (t >= off) ? ts[t - off] : 0;
        __syncthreads();
        ts[t] += x;
        __syncthreads();
    }
    int run = ts[t] - s;
#pragma unroll
    for (int j = 0; j < 4; j++) {
        run += v[j];
        int i = base + j;
        if (i < N) tmp[i] = run;
    }
    if (t == 255) blk[blockIdx.x] = ts[255];
}

// pass B: exclusive scan of block totals (single block)
__global__ void scanB_kernel(int* __restrict__ blk, int nb) {
    __shared__ int ts[128];
    int t = threadIdx.x;
    int v = (t < nb) ? blk[t] : 0;
    ts[t] = v;
    __syncthreads();
    for (int off = 1; off < 128; off <<= 1) {
        int x = (t >= off) ? ts[t - off] : 0;
        __syncthreads();
        ts[t] += x;
        __syncthreads();
    }
    if (t < nb) blk[t] = ts[t] - v;
}

// pass C: final exclusive row_ptr + cursor copy
__global__ void scanC_kernel(const int* __restrict__ tmp, const int* __restrict__ blk,
                             int N, int E, int* __restrict__ rowp, int* __restrict__ cur) {
    int i = blockIdx.x * blockDim.x + threadIdx.x;
    if (i < N) {
        int b = i >> 10;
        int local = i & 1023;
        int excl = blk[b] + (local ? tmp[i - 1] : 0);
        rowp[i] = excl;
        cur[i] = excl;
    }
    if (i == 0) rowp[N] = E;
}

// packed edge record: {src, weight-bits}
__global__ void fill_kernel(const int* __restrict__ src, const int* __restrict__ dst, int E,
                            const float* __restrict__ dis, int* __restrict__ cur,
                            int2* __restrict__ ecw) {
    int e = blockIdx.x * blockDim.x + threadIdx.x;
    if (e < E) {
        int s = src[e], d = dst[e];
        int pos = atomicAdd(&cur[d], 1);
        ecw[pos] = make_int2(s, __float_as_int(dis[s] * dis[d]));
    }
}

// ---------------- GEMM: C[M,64] = f(A[M,K]) @ W[K,64] ----------------

template<int K, bool AFFINE, bool BIAS, bool RELU, bool STATS>
__global__ __launch_bounds__(256) void gemm_kernel(
    const float* __restrict__ A, const float* __restrict__ W,
    const float* __restrict__ scale, const float* __restrict__ shift,
    const float* __restrict__ bias, float* __restrict__ C,
    float* __restrict__ stats, int M)
{
    __shared__ float As[64][K + 1];
    __shared__ float Ws[K][64];
    __shared__ float bs[64], bq[64];
    int t = threadIdx.x;
    int row0 = blockIdx.x * 64;

    for (int q = t; q < K * 16; q += 256) {
        int k = q >> 4, c4 = (q & 15) << 2;
        float4 w = *reinterpret_cast<const float4*>(&W[k * 64 + c4]);
        *reinterpret_cast<float4*>(&Ws[k][c4]) = w;
    }
    for (int q = t; q < 64 * (K / 4); q += 256) {
        int r = q / (K / 4);
        int k4 = (q % (K / 4)) * 4;
        int row = row0 + r;
        float4 a;
        if (row < M) {
            a = *reinterpret_cast<const float4*>(&A[(size_t)row * K + k4]);
            if (AFFINE) {
                a.x = a.x * scale[k4]     + shift[k4];
                a.y = a.y * scale[k4 + 1] + shift[k4 + 1];
                a.z = a.z * scale[k4 + 2] + shift[k4 + 2];
                a.w = a.w * scale[k4 + 3] + shift[k4 + 3];
            }
        } else {
            a = make_float4(0.f, 0.f, 0.f, 0.f);
        }
        As[r][k4] = a.x; As[r][k4 + 1] = a.y; As[r][k4 + 2] = a.z; As[r][k4 + 3] = a.w;
    }
    __syncthreads();

    int ty = t >> 4, tx = t & 15;
    int r0 = ty * 4, c0 = tx * 4;
    float acc[4][4] = {};
#pragma unroll 8
    for (int k = 0; k < K; k++) {
        float a0 = As[r0][k], a1 = As[r0 + 1][k], a2 = As[r0 + 2][k], a3 = As[r0 + 3][k];
        float4 w = *reinterpret_cast<const float4*>(&Ws[k][c0]);
        acc[0][0] += a0 * w.x; acc[0][1] += a0 * w.y; acc[0][2] += a0 * w.z; acc[0][3] += a0 * w.w;
        acc[1][0] += a1 * w.x; acc[1][1] += a1 * w.y; acc[1][2] += a1 * w.z; acc[1][3] += a1 * w.w;
        acc[2][0] += a2 * w.x; acc[2][1] += a2 * w.y; acc[2][2] += a2 * w.z; acc[2][3] += a2 * w.w;
        acc[3][0] += a3 * w.x; acc[3][1] += a3 * w.y; acc[3][2] += a3 * w.z; acc[3][3] += a3 * w.w;
    }

    if (STATS) {
        if (t < 64) { bs[t] = 0.f; bq[t] = 0.f; }
        __syncthreads();
    }
    float ssum[4] = {0.f, 0.f, 0.f, 0.f}, ssq[4] = {0.f, 0.f, 0.f, 0.f};
#pragma unroll
    for (int i = 0; i < 4; i++) {
        int row = row0 + r0 + i;
        if (row < M) {
            float4 v;
            float* vp = &v.x;
#pragma unroll
            for (int j = 0; j < 4; j++) {
                float x = acc[i][j];
                if (BIAS) x += bias[c0 + j];
                if (RELU) x = fmaxf(x, 0.f);
                vp[j] = x;
                if (STATS) { ssum[j] += x; ssq[j] += x * x; }
            }
            *reinterpret_cast<float4*>(&C[(size_t)row * 64 + c0]) = v;
        }
    }
    if (STATS) {
#pragma unroll
        for (int j = 0; j < 4; j++) {
            atomicAdd(&bs[c0 + j], ssum[j]);
            atomicAdd(&bq[c0 + j], ssq[j]);
        }
        __syncthreads();
        if (t < 64) {
            atomicAdd(&stats[t], bs[t]);
            atomicAdd(&stats[64 + t], bq[t]);
        }
    }
}

// ---------------- edge aggregation ----------------
// one wave = one node group; lane = channel. 8-deep pipelined gather:
// predicated clamp => no scalar tail, 8 independent H-row loads in flight.

template<bool RELU>
__global__ __launch_bounds__(256) void agg_kernel(
    const float* __restrict__ H, const int* __restrict__ rowp,
    const int2* __restrict__ ecw,
    const float* __restrict__ dis, const float* __restrict__ bias,
    float* __restrict__ Hout, float* __restrict__ stats, int N)
{
    __shared__ float bs[64], bq[64];
    int t = threadIdx.x;
    int lane = t & 63;
    int base = (blockIdx.x * 4 + (t >> 6)) * 8;
    float b = bias[lane];
    float ssum = 0.f, ssq = 0.f;
    for (int u = 0; u < 8; u++) {
        int n = base + u;
        if (n >= N) break;
        int e0 = rowp[n], e1 = rowp[n + 1];
        float acc = 0.f;
        for (int e = e0; e < e1; e += 8) {
            int   idx[8];
            float ww[8];
#pragma unroll
            for (int j = 0; j < 8; j++) {
                int ee = e + j;
                bool ok = ee < e1;
                int2 p = ecw[ok ? ee : e0];
                idx[j] = p.x;
                ww[j]  = ok ? __int_as_float(p.y) : 0.f;
            }
            float h[8];
#pragma unroll
            for (int j = 0; j < 8; j++)
                h[j] = H[(size_t)idx[j] * 64 + lane];
#pragma unroll
            for (int j = 0; j < 8; j++)
                acc += h[j] * ww[j];
        }
        float dn = dis[n];
        acc += H[(size_t)n * 64 + lane] * (dn * dn);
        acc += b;
        if (RELU) acc = fmaxf(acc, 0.f);
        Hout[(size_t)n * 64 + lane] = acc;
        ssum += acc;
        ssq += acc * acc;
    }
    if (t < 64) { bs[t] = 0.f; bq[t] = 0.f; }
    __syncthreads();
    atomicAdd(&bs[lane], ssum);
    atomicAdd(&bq[lane], ssq);
    __syncthreads();
    if (t < 64) {
        atomicAdd(&stats[t], bs[t]);
        atomicAdd(&stats[64 + t], bq[t]);
    }
}

// ---------------- BN prep: stats -> (scale, shift) ----------------

__global__ void bnprep_kernel(const float* __restrict__ stats, const float* __restrict__ g,
                              const float* __restrict__ b, float* __restrict__ ss, float cntInv) {
    int c = threadIdx.x;
    float mean = stats[c] * cntInv;
    float var = stats[64 + c] * cntInv - mean * mean;
    float sc = g[c] * rsqrtf(var + 1e-5f);
    ss[c] = sc;
    ss[64 + c] = b[c] - mean * sc;
}

// ---------------- pooling (batch sorted -> run-length accumulate) ----------------

__global__ __launch_bounds__(256) void pool_kernel(
    const float* __restrict__ H, const int* __restrict__ batch,
    const float* __restrict__ ss, float* __restrict__ P, int N)
{
    int t = threadIdx.x;
    int lane = t & 63;
    int base = (blockIdx.x * 4 + (t >> 6)) * 8;
    float sc = ss[lane], sh = ss[64 + lane];
    float acc = 0.f;
    int gprev = -1;
    for (int u = 0; u < 8; u++) {
        int n = base + u;
        if (n >= N) break;
        int g = batch[n];
        if (g != gprev) {
            if (gprev >= 0) atomicAdd(&P[(size_t)gprev * 64 + lane], acc);
            acc = 0.f;
            gprev = g;
        }
        acc += H[(size_t)n * 64 + lane] * sc + sh;
    }
    if (gprev >= 0) atomicAdd(&P[(size_t)gprev * 64 + lane], acc);
}

// ---------------- output head ----------------

__global__ __launch_bounds__(256) void final_kernel(
    const float* __restrict__ P, const float* __restrict__ ss,
    const float* __restrict__ outw, const float* __restrict__ outb,
    float* __restrict__ out, int G)
{
    int t = threadIdx.x;
    int lane = t & 63;
    int g = blockIdx.x * 4 + (t >> 6);
    if (g >= G) return;
    float v = (P[(size_t)g * 64 + lane] * ss[lane] + ss[64 + lane]) * outw[lane];
#pragma unroll
    for (int off = 32; off >= 1; off >>= 1) v += __shfl_xor(v, off, 64);
    if (lane == 0) out[g] = v + outb[0];
}

// ---------------- launch ----------------

extern "C" void kernel_launch(void* const* d_in, const int* in_sizes, int n_in,
                              void* d_out, int out_size, void* d_ws, size_t ws_size,
                              hipStream_t stream)
{
    const float* x      = (const float*)d_in[0];
    const int*   ei     = (const int*)d_in[1];
    const int*   batch  = (const int*)d_in[2];
    const float* w1     = (const float*)d_in[3];
    const float* b1     = (const float*)d_in[4];
    const float* bn1_g  = (const float*)d_in[5];
    const float* bn1_b  = (const float*)d_in[6];
    const float* conv_w = (const float*)d_in[7];
    const float* conv_b = (const float*)d_in[8];
    const float* bnc_g  = (const float*)d_in[9];
    const float* bnc_b  = (const float*)d_in[10];
    const float* mlp_w  = (const float*)d_in[11];
    const float* mlp_b  = (const float*)d_in[12];
    const float* bnm_g  = (const float*)d_in[13];
    const float* bnm_b  = (const float*)d_in[14];
    const float* out_w  = (const float*)d_in[15];
    const float* out_b  = (const float*)d_in[16];
    float* out = (float*)d_out;

    const int N = in_sizes[0] / N_FEAT;   // 100000 nodes
    const int E = in_sizes[1] / 2;        // 3.2M edges
    const int G = out_size;               // 4096 graphs
    const int* esrc = ei;
    const int* edst = ei + E;

    char* ws = (char*)d_ws;
    size_t off = 0;
    auto alloc = [&](size_t bytes) {
        size_t cur = off;
        off += (bytes + 255) & ~(size_t)255;
        return (void*)(ws + cur);
    };

    int*   deg   = (int*)alloc((size_t)N * 4);
    float* dis   = (float*)alloc((size_t)N * 4);
    int*   rtmp  = (int*)alloc((size_t)N * 4);
    int*   rowp  = (int*)alloc((size_t)(N + 1) * 4);
    int*   cur   = (int*)alloc((size_t)N * 4);
    int*   blk   = (int*)alloc(256 * 4);
    int2*  ecw   = (int2*)alloc((size_t)E * 8);
    float* bufA  = (float*)alloc((size_t)(N + 64) * 64 * 4);
    float* bufB  = (float*)alloc((size_t)(N + 64) * 64 * 4);
    float* stats = (float*)alloc(7 * 128 * 4);
    float* ssbuf = (float*)alloc(7 * 128 * 4);
    float* P     = (float*)alloc((size_t)G * 64 * 4);
    float* pA    = (float*)alloc((size_t)G * 64 * 4);
    float* pB    = (float*)alloc((size_t)G * 64 * 4);

    hipMemsetAsync(deg, 0, (size_t)N * 4, stream);
    hipMemsetAsync(stats, 0, 7 * 128 * 4, stream);
    hipMemsetAsync(P, 0, (size_t)G * 64 * 4, stream);

    // graph prep
    hist_kernel<<<(E + 255) / 256, 256, 0, stream>>>(edst, E, deg);
    dis_kernel<<<(N + 255) / 256, 256, 0, stream>>>(deg, dis, N);
    int nchunk = (N + 1023) / 1024;
    scanA_kernel<<<nchunk, 256, 0, stream>>>(deg, N, rtmp, blk);
    scanB_kernel<<<1, 128, 0, stream>>>(blk, nchunk);
    scanC_kernel<<<(N + 255) / 256, 256, 0, stream>>>(rtmp, blk, N, E, rowp, cur);
    fill_kernel<<<(E + 255) / 256, 256, 0, stream>>>(esrc, edst, E, dis, cur, ecw);

    int gemmN_grid = (N + 63) / 64;
    int aggN_grid = (N + 31) / 32;

    // layer 1: x @ w1 -> agg (+b1, relu, stats0)
    gemm_kernel<128, false, false, false, false><<<gemmN_grid, 256, 0, stream>>>(
        x, w1, nullptr, nullptr, nullptr, bufA, nullptr, N);
    agg_kernel<true><<<aggN_grid, 256, 0, stream>>>(
        bufA, rowp, ecw, dis, b1, bufB, stats, N);
    bnprep_kernel<<<1, 64, 0, stream>>>(stats, bn1_g, bn1_b, ssbuf, 1.0f / N);

    // conv layers
    for (int i = 0; i < 3; i++) {
        const float* W  = conv_w + (size_t)i * 64 * 64;
        const float* bb = conv_b + (size_t)i * 64;
        float* st     = stats + (size_t)(1 + i) * 128;
        float* ss_in  = ssbuf + (size_t)i * 128;
        float* ss_out = ssbuf + (size_t)(1 + i) * 128;
        gemm_kernel<64, true, false, false, false><<<gemmN_grid, 256, 0, stream>>>(
            bufB, W, ss_in, ss_in + 64, nullptr, bufA, nullptr, N);
        agg_kernel<false><<<aggN_grid, 256, 0, stream>>>(
            bufA, rowp, ecw, dis, bb, bufB, st, N);
        bnprep_kernel<<<1, 64, 0, stream>>>(st, bnc_g + (size_t)i * 64, bnc_b + (size_t)i * 64,
                                            ss_out, 1.0f / N);
    }

    // pooling (applies conv3 BN)
    pool_kernel<<<aggN_grid, 256, 0, stream>>>(bufB, batch, ssbuf + 3 * 128, P, N);

    // MLP
    int gemmG_grid = (G + 63) / 64;
    gemm_kernel<64, false, true, true, true><<<gemmG_grid, 256, 0, stream>>>(
        P, mlp_w, nullptr, nullptr, mlp_b, pA, stats + 4 * 128, G);
    bnprep_kernel<<<1, 64, 0, stream>>>(stats + 4 * 128, bnm_g, bnm_b, ssbuf + 4 * 128, 1.0f / G);

    gemm_kernel<64, true, true, true, true><<<gemmG_grid, 256, 0, stream>>>(
        pA, mlp_w + 64 * 64, ssbuf + 4 * 128, ssbuf + 4 * 128 + 64,
        mlp_b + 64, pB, stats + 5 * 128, G);
    bnprep_kernel<<<1, 64, 0, stream>>>(stats + 5 * 128, bnm_g + 64, bnm_b + 64, ssbuf + 5 * 128, 1.0f / G);

    gemm_kernel<64, true, true, true, true><<<gemmG_grid, 256, 0, stream>>>(
        pB, mlp_w + 2 * 64 * 64, ssbuf + 5 * 128, ssbuf + 5 * 128 + 64,
        mlp_b + 2 * 64, pA, stats + 6 * 128, G);
    bnprep_kernel<<<1, 64, 0, stream>>>(stats + 6 * 128, bnm_g + 2 * 64, bnm_b + 2 * 64, ssbuf + 6 * 128, 1.0f / G);

    final_kernel<<<(G + 3) / 4, 256, 0, stream>>>(pA, ssbuf + 6 * 128, out_w, out_b, out, G);
}

// Round 6
// 1170.632 us; speedup vs baseline: 1.7576x; 1.0408x over previous
//
#include <hip/hip_runtime.h>
#include <hip/hip_bf16.h>

#define N_FEAT 128
#define DIM 64

// ---------------- graph prep ----------------

__global__ void hist_kernel(const int* __restrict__ dst, int E, int* __restrict__ cnt) {
    int e = blockIdx.x * blockDim.x + threadIdx.x;
    if (e < E) atomicAdd(&cnt[dst[e]], 1);
}

__global__ void dis_kernel(const int* __restrict__ cnt, float* __restrict__ dis, int N) {
    int i = blockIdx.x * blockDim.x + threadIdx.x;
    if (i < N) dis[i] = rsqrtf((float)cnt[i] + 1.0f);
}

// pass A: per-block (1024 elems) inclusive scan of PADDED degree (deg rounded up to 8)
__global__ void scanA_kernel(const int* __restrict__ cnt, int N,
                             int* __restrict__ tmp, int* __restrict__ blk) {
    __shared__ int ts[256];
    int t = threadIdx.x;
    int base = blockIdx.x * 1024 + t * 4;
    int v[4];
    int s = 0;
#pragma unroll
    for (int j = 0; j < 4; j++) {
        int i = base + j;
        v[j] = (i < N) ? ((cnt[i] + 7) & ~7) : 0;
        s += v[j];
    }
    ts[t] = s;
    __syncthreads();
    for (int off = 1; off < 256; off <<= 1) {
        int x = (t >= off) ? ts[t - off] : 0;
        __syncthreads();
        ts[t] += x;
        __syncthreads();
    }
    int run = ts[t] - s;
#pragma unroll
    for (int j = 0; j < 4; j++) {
        run += v[j];
        int i = base + j;
        if (i < N) tmp[i] = run;
    }
    if (t == 255) blk[blockIdx.x] = ts[255];
}

// pass B: exclusive scan of block totals (single block)
__global__ void scanB_kernel(int* __restrict__ blk, int nb) {
    __shared__ int ts[128];
    int t = threadIdx.x;
    int v = (t < nb) ? blk[t] : 0;
    ts[t] = v;
    __syncthreads();
    for (int off = 1; off < 128; off <<= 1) {
        int x = (t >= off) ? ts[t - off] : 0;
        __syncthreads();
        ts[t] += x;
        __syncthreads();
    }
    if (t < nb) blk[t] = ts[t] - v;
}

// pass C: final exclusive padded row_ptr + cursor copy
__global__ void scanC_kernel(const int* __restrict__ tmp, const int* __restrict__ blk,
                             const int* __restrict__ cnt,
                             int N, int* __restrict__ rowp, int* __restrict__ cur) {
    int i = blockIdx.x * blockDim.x + threadIdx.x;
    if (i < N) {
        int b = i >> 10;
        int local = i & 1023;
        int excl = blk[b] + (local ? tmp[i - 1] : 0);
        rowp[i] = excl;
        cur[i] = excl;
        if (i == N - 1) rowp[N] = excl + ((cnt[i] + 7) & ~7);
    }
}

// packed edge record: {src byte-offset (s*256), weight-bits}
__global__ void fill_kernel(const int* __restrict__ src, const int* __restrict__ dst, int E,
                            const float* __restrict__ dis, int* __restrict__ cur,
                            int2* __restrict__ ecw) {
    int e = blockIdx.x * blockDim.x + threadIdx.x;
    if (e < E) {
        int s = src[e], d = dst[e];
        int pos = atomicAdd(&cur[d], 1);
        ecw[pos] = make_int2(s << 8, __float_as_int(dis[s] * dis[d]));
    }
}

// pad tail of each row with {offset 0, weight 0} records
__global__ void pad_kernel(const int* __restrict__ cur, const int* __restrict__ rowp,
                           int2* __restrict__ ecw, int N) {
    int i = blockIdx.x * blockDim.x + threadIdx.x;
    if (i < N) {
        int p = cur[i], e = rowp[i + 1];
        for (; p < e; p++) ecw[p] = make_int2(0, 0);
    }
}

// ---------------- GEMM: C[M,64] = f(A[M,K]) @ W[K,64] ----------------

template<int K, bool AFFINE, bool BIAS, bool RELU, bool STATS>
__global__ __launch_bounds__(256) void gemm_kernel(
    const float* __restrict__ A, const float* __restrict__ W,
    const float* __restrict__ scale, const float* __restrict__ shift,
    const float* __restrict__ bias, float* __restrict__ C,
    float* __restrict__ stats, int M)
{
    __shared__ float As[64][K + 4];   // +4 keeps float4 rows 16B-aligned
    __shared__ float Ws[K][64];
    __shared__ float bs[64], bq[64];
    int t = threadIdx.x;
    int row0 = blockIdx.x * 64;

    for (int q = t; q < K * 16; q += 256) {
        int k = q >> 4, c4 = (q & 15) << 2;
        float4 w = *reinterpret_cast<const float4*>(&W[k * 64 + c4]);
        *reinterpret_cast<float4*>(&Ws[k][c4]) = w;
    }
    for (int q = t; q < 64 * (K / 4); q += 256) {
        int r = q / (K / 4);
        int k4 = (q % (K / 4)) * 4;
        int row = row0 + r;
        float4 a;
        if (row < M) {
            a = *reinterpret_cast<const float4*>(&A[(size_t)row * K + k4]);
            if (AFFINE) {
                a.x = a.x * scale[k4]     + shift[k4];
                a.y = a.y * scale[k4 + 1] + shift[k4 + 1];
                a.z = a.z * scale[k4 + 2] + shift[k4 + 2];
                a.w = a.w * scale[k4 + 3] + shift[k4 + 3];
            }
        } else {
            a = make_float4(0.f, 0.f, 0.f, 0.f);
        }
        *reinterpret_cast<float4*>(&As[r][k4]) = a;
    }
    __syncthreads();

    int ty = t >> 4, tx = t & 15;
    int r0 = ty * 4, c0 = tx * 4;
    float acc[4][4] = {};
#pragma unroll 2
    for (int k = 0; k < K; k += 4) {
        float4 A0 = *reinterpret_cast<const float4*>(&As[r0 + 0][k]);
        float4 A1 = *reinterpret_cast<const float4*>(&As[r0 + 1][k]);
        float4 A2 = *reinterpret_cast<const float4*>(&As[r0 + 2][k]);
        float4 A3 = *reinterpret_cast<const float4*>(&As[r0 + 3][k]);
        float ar[4][4] = {{A0.x, A0.y, A0.z, A0.w}, {A1.x, A1.y, A1.z, A1.w},
                          {A2.x, A2.y, A2.z, A2.w}, {A3.x, A3.y, A3.z, A3.w}};
#pragma unroll
        for (int kk = 0; kk < 4; kk++) {
            float4 w = *reinterpret_cast<const float4*>(&Ws[k + kk][c0]);
#pragma unroll
            for (int i = 0; i < 4; i++) {
                acc[i][0] += ar[i][kk] * w.x;
                acc[i][1] += ar[i][kk] * w.y;
                acc[i][2] += ar[i][kk] * w.z;
                acc[i][3] += ar[i][kk] * w.w;
            }
        }
    }

    if (STATS) {
        if (t < 64) { bs[t] = 0.f; bq[t] = 0.f; }
        __syncthreads();
    }
    float ssum[4] = {0.f, 0.f, 0.f, 0.f}, ssq[4] = {0.f, 0.f, 0.f, 0.f};
#pragma unroll
    for (int i = 0; i < 4; i++) {
        int row = row0 + r0 + i;
        if (row < M) {
            float4 v;
            float* vp = &v.x;
#pragma unroll
            for (int j = 0; j < 4; j++) {
                float x = acc[i][j];
                if (BIAS) x += bias[c0 + j];
                if (RELU) x = fmaxf(x, 0.f);
                vp[j] = x;
                if (STATS) { ssum[j] += x; ssq[j] += x * x; }
            }
            *reinterpret_cast<float4*>(&C[(size_t)row * 64 + c0]) = v;
        }
    }
    if (STATS) {
#pragma unroll
        for (int j = 0; j < 4; j++) {
            atomicAdd(&bs[c0 + j], ssum[j]);
            atomicAdd(&bq[c0 + j], ssq[j]);
        }
        __syncthreads();
        if (t < 64) {
            atomicAdd(&stats[t], bs[t]);
            atomicAdd(&stats[64 + t], bq[t]);
        }
    }
}

// ---------------- edge aggregation ----------------
// one wave = one node; lane = channel. Rows padded to multiple of 8:
// no predication, 8 independent gathers in flight, 32-bit byte offsets.

template<bool RELU>
__global__ __launch_bounds__(256) void agg_kernel(
    const float* __restrict__ H, const int* __restrict__ rowp,
    const int2* __restrict__ ecw,
    const float* __restrict__ dis, const float* __restrict__ bias,
    float* __restrict__ Hout, float* __restrict__ stats, int N)
{
    __shared__ float bs[64], bq[64];
    int t = threadIdx.x;
    int lane = t & 63;
    unsigned lane4 = (unsigned)lane << 2;
    const char* Hb = (const char*)H;
    int base = (blockIdx.x * 4 + (t >> 6)) * 8;
    float b = bias[lane];
    float ssum = 0.f, ssq = 0.f;
    for (int u = 0; u < 8; u++) {
        int n = base + u;
        if (n >= N) break;
        int e0 = rowp[n], e1 = rowp[n + 1];
        float acc = 0.f;
        for (int e = e0; e < e1; e += 8) {
            int2 p[8];
#pragma unroll
            for (int j = 0; j < 8; j++) p[j] = ecw[e + j];
            float h[8];
#pragma unroll
            for (int j = 0; j < 8; j++)
                h[j] = *(const float*)(Hb + ((unsigned)p[j].x + lane4));
#pragma unroll
            for (int j = 0; j < 8; j++)
                acc += h[j] * __int_as_float(p[j].y);
        }
        float dn = dis[n];
        acc += H[(size_t)n * 64 + lane] * (dn * dn);
        acc += b;
        if (RELU) acc = fmaxf(acc, 0.f);
        Hout[(size_t)n * 64 + lane] = acc;
        ssum += acc;
        ssq += acc * acc;
    }
    if (t < 64) { bs[t] = 0.f; bq[t] = 0.f; }
    __syncthreads();
    atomicAdd(&bs[lane], ssum);
    atomicAdd(&bq[lane], ssq);
    __syncthreads();
    if (t < 64) {
        atomicAdd(&stats[t], bs[t]);
        atomicAdd(&stats[64 + t], bq[t]);
    }
}

// ---------------- BN prep: stats -> (scale, shift) ----------------

__global__ void bnprep_kernel(const float* __restrict__ stats, const float* __restrict__ g,
                              const float* __restrict__ b, float* __restrict__ ss, float cntInv) {
    int c = threadIdx.x;
    float mean = stats[c] * cntInv;
    float var = stats[64 + c] * cntInv - mean * mean;
    float sc = g[c] * rsqrtf(var + 1e-5f);
    ss[c] = sc;
    ss[64 + c] = b[c] - mean * sc;
}

// ---------------- pooling (batch sorted -> run-length accumulate) ----------------

__global__ __launch_bounds__(256) void pool_kernel(
    const float* __restrict__ H, const int* __restrict__ batch,
    const float* __restrict__ ss, float* __restrict__ P, int N)
{
    int t = threadIdx.x;
    int lane = t & 63;
    int base = (blockIdx.x * 4 + (t >> 6)) * 8;
    float sc = ss[lane], sh = ss[64 + lane];
    float acc = 0.f;
    int gprev = -1;
    for (int u = 0; u < 8; u++) {
        int n = base + u;
        if (n >= N) break;
        int g = batch[n];
        if (g != gprev) {
            if (gprev >= 0) atomicAdd(&P[(size_t)gprev * 64 + lane], acc);
            acc = 0.f;
            gprev = g;
        }
        acc += H[(size_t)n * 64 + lane] * sc + sh;
    }
    if (gprev >= 0) atomicAdd(&P[(size_t)gprev * 64 + lane], acc);
}

// ---------------- output head ----------------

__global__ __launch_bounds__(256) void final_kernel(
    const float* __restrict__ P, const float* __restrict__ ss,
    const float* __restrict__ outw, const float* __restrict__ outb,
    float* __restrict__ out, int G)
{
    int t = threadIdx.x;
    int lane = t & 63;
    int g = blockIdx.x * 4 + (t >> 6);
    if (g >= G) return;
    float v = (P[(size_t)g * 64 + lane] * ss[lane] + ss[64 + lane]) * outw[lane];
#pragma unroll
    for (int off = 32; off >= 1; off >>= 1) v += __shfl_xor(v, off, 64);
    if (lane == 0) out[g] = v + outb[0];
}

// ---------------- launch ----------------

extern "C" void kernel_launch(void* const* d_in, const int* in_sizes, int n_in,
                              void* d_out, int out_size, void* d_ws, size_t ws_size,
                              hipStream_t stream)
{
    const float* x      = (const float*)d_in[0];
    const int*   ei     = (const int*)d_in[1];
    const int*   batch  = (const int*)d_in[2];
    const float* w1     = (const float*)d_in[3];
    const float* b1     = (const float*)d_in[4];
    const float* bn1_g  = (const float*)d_in[5];
    const float* bn1_b  = (const float*)d_in[6];
    const float* conv_w = (const float*)d_in[7];
    const float* conv_b = (const float*)d_in[8];
    const float* bnc_g  = (const float*)d_in[9];
    const float* bnc_b  = (const float*)d_in[10];
    const float* mlp_w  = (const float*)d_in[11];
    const float* mlp_b  = (const float*)d_in[12];
    const float* bnm_g  = (const float*)d_in[13];
    const float* bnm_b  = (const float*)d_in[14];
    const float* out_w  = (const float*)d_in[15];
    const float* out_b  = (const float*)d_in[16];
    float* out = (float*)d_out;

    const int N = in_sizes[0] / N_FEAT;   // 100000 nodes
    const int E = in_sizes[1] / 2;        // 3.2M edges
    const int G = out_size;               // 4096 graphs
    const int* esrc = ei;
    const int* edst = ei + E;

    char* ws = (char*)d_ws;
    size_t off = 0;
    auto alloc = [&](size_t bytes) {
        size_t cur = off;
        off += (bytes + 255) & ~(size_t)255;
        return (void*)(ws + cur);
    };

    int*   deg   = (int*)alloc((size_t)N * 4);
    float* dis   = (float*)alloc((size_t)N * 4);
    int*   rtmp  = (int*)alloc((size_t)N * 4);
    int*   rowp  = (int*)alloc((size_t)(N + 1) * 4);
    int*   cur   = (int*)alloc((size_t)N * 4);
    int*   blk   = (int*)alloc(256 * 4);
    int2*  ecw   = (int2*)alloc(((size_t)E + 8ull * N) * 8);   // padded CSR
    float* bufA  = (float*)alloc((size_t)(N + 64) * 64 * 4);
    float* bufB  = (float*)alloc((size_t)(N + 64) * 64 * 4);
    float* stats = (float*)alloc(7 * 128 * 4);
    float* ssbuf = (float*)alloc(7 * 128 * 4);
    float* P     = (float*)alloc((size_t)G * 64 * 4);
    float* pA    = (float*)alloc((size_t)G * 64 * 4);
    float* pB    = (float*)alloc((size_t)G * 64 * 4);

    hipMemsetAsync(deg, 0, (size_t)N * 4, stream);
    hipMemsetAsync(stats, 0, 7 * 128 * 4, stream);
    hipMemsetAsync(P, 0, (size_t)G * 64 * 4, stream);

    // graph prep
    hist_kernel<<<(E + 255) / 256, 256, 0, stream>>>(edst, E, deg);
    dis_kernel<<<(N + 255) / 256, 256, 0, stream>>>(deg, dis, N);
    int nchunk = (N + 1023) / 1024;
    scanA_kernel<<<nchunk, 256, 0, stream>>>(deg, N, rtmp, blk);
    scanB_kernel<<<1, 128, 0, stream>>>(blk, nchunk);
    scanC_kernel<<<(N + 255) / 256, 256, 0, stream>>>(rtmp, blk, deg, N, rowp, cur);
    fill_kernel<<<(E + 255) / 256, 256, 0, stream>>>(esrc, edst, E, dis, cur, ecw);
    pad_kernel<<<(N + 255) / 256, 256, 0, stream>>>(cur, rowp, ecw, N);

    int gemmN_grid = (N + 63) / 64;
    int aggN_grid = (N + 31) / 32;

    // layer 1: x @ w1 -> agg (+b1, relu, stats0)
    gemm_kernel<128, false, false, false, false><<<gemmN_grid, 256, 0, stream>>>(
        x, w1, nullptr, nullptr, nullptr, bufA, nullptr, N);
    agg_kernel<true><<<aggN_grid, 256, 0, stream>>>(
        bufA, rowp, ecw, dis, b1, bufB, stats, N);
    bnprep_kernel<<<1, 64, 0, stream>>>(stats, bn1_g, bn1_b, ssbuf, 1.0f / N);

    // conv layers
    for (int i = 0; i < 3; i++) {
        const float* W  = conv_w + (size_t)i * 64 * 64;
        const float* bb = conv_b + (size_t)i * 64;
        float* st     = stats + (size_t)(1 + i) * 128;
        float* ss_in  = ssbuf + (size_t)i * 128;
        float* ss_out = ssbuf + (size_t)(1 + i) * 128;
        gemm_kernel<64, true, false, false, false><<<gemmN_grid, 256, 0, stream>>>(
            bufB, W, ss_in, ss_in + 64, nullptr, bufA, nullptr, N);
        agg_kernel<false><<<aggN_grid, 256, 0, stream>>>(
            bufA, rowp, ecw, dis, bb, bufB, st, N);
        bnprep_kernel<<<1, 64, 0, stream>>>(st, bnc_g + (size_t)i * 64, bnc_b + (size_t)i * 64,
                                            ss_out, 1.0f / N);
    }

    // pooling (applies conv3 BN)
    pool_kernel<<<aggN_grid, 256, 0, stream>>>(bufB, batch, ssbuf + 3 * 128, P, N);

    // MLP
    int gemmG_grid = (G + 63) / 64;
    gemm_kernel<64, false, true, true, true><<<gemmG_grid, 256, 0, stream>>>(
        P, mlp_w, nullptr, nullptr, mlp_b, pA, stats + 4 * 128, G);
    bnprep_kernel<<<1, 64, 0, stream>>>(stats + 4 * 128, bnm_g, bnm_b, ssbuf + 4 * 128, 1.0f / G);

    gemm_kernel<64, true, true, true, true><<<gemmG_grid, 256, 0, stream>>>(
        pA, mlp_w + 64 * 64, ssbuf + 4 * 128, ssbuf + 4 * 128 + 64,
        mlp_b + 64, pB, stats + 5 * 128, G);
    bnprep_kernel<<<1, 64, 0, stream>>>(stats + 5 * 128, bnm_g + 64, bnm_b + 64, ssbuf + 5 * 128, 1.0f / G);

    gemm_kernel<64, true, true, true, true><<<gemmG_grid, 256, 0, stream>>>(
        pB, mlp_w + 2 * 64 * 64, ssbuf + 5 * 128, ssbuf + 5 * 128 + 64,
        mlp_b + 2 * 64, pA, stats + 6 * 128, G);
    bnprep_kernel<<<1, 64, 0, stream>>>(stats + 6 * 128, bnm_g + 2 * 64, bnm_b + 2 * 64, ssbuf + 6 * 128, 1.0f / G);

    final_kernel<<<(G + 3) / 4, 256, 0, stream>>>(pA, ssbuf + 6 * 128, out_w, out_b, out, G);
}

// Round 7
// 1130.859 us; speedup vs baseline: 1.8194x; 1.0352x over previous
//
#include <hip/hip_runtime.h>
#include <hip/hip_bf16.h>

#define N_FEAT 128
#define DIM 64

// ---------------- graph prep ----------------

__global__ void hist_kernel(const int* __restrict__ dst, int E, int* __restrict__ cnt) {
    int e = blockIdx.x * blockDim.x + threadIdx.x;
    if (e < E) atomicAdd(&cnt[dst[e]], 1);
}

__global__ void dis_kernel(const int* __restrict__ cnt, float* __restrict__ dis, int N) {
    int i = blockIdx.x * blockDim.x + threadIdx.x;
    if (i < N) dis[i] = rsqrtf((float)cnt[i] + 1.0f);
}

// pass A: per-block (1024 elems) inclusive scan of PADDED degree (deg rounded up to 8)
__global__ void scanA_kernel(const int* __restrict__ cnt, int N,
                             int* __restrict__ tmp, int* __restrict__ blk) {
    __shared__ int ts[256];
    int t = threadIdx.x;
    int base = blockIdx.x * 1024 + t * 4;
    int v[4];
    int s = 0;
#pragma unroll
    for (int j = 0; j < 4; j++) {
        int i = base + j;
        v[j] = (i < N) ? ((cnt[i] + 7) & ~7) : 0;
        s += v[j];
    }
    ts[t] = s;
    __syncthreads();
    for (int off = 1; off < 256; off <<= 1) {
        int x = (t >= off) ? ts[t - off] : 0;
        __syncthreads();
        ts[t] += x;
        __syncthreads();
    }
    int run = ts[t] - s;
#pragma unroll
    for (int j = 0; j < 4; j++) {
        run += v[j];
        int i = base + j;
        if (i < N) tmp[i] = run;
    }
    if (t == 255) blk[blockIdx.x] = ts[255];
}

// pass B: exclusive scan of block totals (single block)
__global__ void scanB_kernel(int* __restrict__ blk, int nb) {
    __shared__ int ts[128];
    int t = threadIdx.x;
    int v = (t < nb) ? blk[t] : 0;
    ts[t] = v;
    __syncthreads();
    for (int off = 1; off < 128; off <<= 1) {
        int x = (t >= off) ? ts[t - off] : 0;
        __syncthreads();
        ts[t] += x;
        __syncthreads();
    }
    if (t < nb) blk[t] = ts[t] - v;
}

// pass C: final exclusive padded row_ptr + cursor copy
__global__ void scanC_kernel(const int* __restrict__ tmp, const int* __restrict__ blk,
                             const int* __restrict__ cnt,
                             int N, int* __restrict__ rowp, int* __restrict__ cur) {
    int i = blockIdx.x * blockDim.x + threadIdx.x;
    if (i < N) {
        int b = i >> 10;
        int local = i & 1023;
        int excl = blk[b] + (local ? tmp[i - 1] : 0);
        rowp[i] = excl;
        cur[i] = excl;
        if (i == N - 1) rowp[N] = excl + ((cnt[i] + 7) & ~7);
    }
}

// XCD-affine CSR fill: 256 edge-slices x 8 xcd-variants. Block (slice, xcd)
// keeps only edges with dst in xcd's node range -> all writes to a given
// CSR region come from one XCD's L2 -> partial 8B line writes merge.
#define NSLICE 256
__global__ __launch_bounds__(256) void fill8_kernel(
    const int* __restrict__ src, const int* __restrict__ dst, int E,
    const float* __restrict__ dis, int* __restrict__ cur,
    int2* __restrict__ ecw, int npx /* nodes per xcd */) {
    int xcd = blockIdx.x & 7;
    int slice = blockIdx.x >> 3;
    int per = (E + NSLICE - 1) / NSLICE;
    int lo = slice * per;
    int hi = min(lo + per, E);
    int dlo = xcd * npx, dhi = dlo + npx;
    for (int e = lo + threadIdx.x; e < hi; e += 256) {
        int d = dst[e];
        if (d >= dlo && d < dhi) {
            int s = src[e];
            int pos = atomicAdd(&cur[d], 1);
            ecw[pos] = make_int2(s << 8, __float_as_int(dis[s] * dis[d]));
        }
    }
}

// pad tail of each row with {offset 0, weight 0} records
__global__ void pad_kernel(const int* __restrict__ cur, const int* __restrict__ rowp,
                           int2* __restrict__ ecw, int N) {
    int i = blockIdx.x * blockDim.x + threadIdx.x;
    if (i < N) {
        int p = cur[i], e = rowp[i + 1];
        for (; p < e; p++) ecw[p] = make_int2(0, 0);
    }
}

// ---------------- GEMM: C[M,64] = f(A[M,K]) @ W[K,64] ----------------

template<int K, bool AFFINE, bool BIAS, bool RELU, bool STATS>
__global__ __launch_bounds__(256) void gemm_kernel(
    const float* __restrict__ A, const float* __restrict__ W,
    const float* __restrict__ scale, const float* __restrict__ shift,
    const float* __restrict__ bias, float* __restrict__ C,
    float* __restrict__ stats, int M)
{
    __shared__ float As[64][K + 4];   // +4 keeps float4 rows 16B-aligned
    __shared__ float Ws[K][64];
    __shared__ float bs[64], bq[64];
    int t = threadIdx.x;
    int row0 = blockIdx.x * 64;

    for (int q = t; q < K * 16; q += 256) {
        int k = q >> 4, c4 = (q & 15) << 2;
        float4 w = *reinterpret_cast<const float4*>(&W[k * 64 + c4]);
        *reinterpret_cast<float4*>(&Ws[k][c4]) = w;
    }
    for (int q = t; q < 64 * (K / 4); q += 256) {
        int r = q / (K / 4);
        int k4 = (q % (K / 4)) * 4;
        int row = row0 + r;
        float4 a;
        if (row < M) {
            a = *reinterpret_cast<const float4*>(&A[(size_t)row * K + k4]);
            if (AFFINE) {
                a.x = a.x * scale[k4]     + shift[k4];
                a.y = a.y * scale[k4 + 1] + shift[k4 + 1];
                a.z = a.z * scale[k4 + 2] + shift[k4 + 2];
                a.w = a.w * scale[k4 + 3] + shift[k4 + 3];
            }
        } else {
            a = make_float4(0.f, 0.f, 0.f, 0.f);
        }
        *reinterpret_cast<float4*>(&As[r][k4]) = a;
    }
    __syncthreads();

    int ty = t >> 4, tx = t & 15;
    int r0 = ty * 4, c0 = tx * 4;
    float acc[4][4] = {};
#pragma unroll 2
    for (int k = 0; k < K; k += 4) {
        float4 A0 = *reinterpret_cast<const float4*>(&As[r0 + 0][k]);
        float4 A1 = *reinterpret_cast<const float4*>(&As[r0 + 1][k]);
        float4 A2 = *reinterpret_cast<const float4*>(&As[r0 + 2][k]);
        float4 A3 = *reinterpret_cast<const float4*>(&As[r0 + 3][k]);
        float ar[4][4] = {{A0.x, A0.y, A0.z, A0.w}, {A1.x, A1.y, A1.z, A1.w},
                          {A2.x, A2.y, A2.z, A2.w}, {A3.x, A3.y, A3.z, A3.w}};
#pragma unroll
        for (int kk = 0; kk < 4; kk++) {
            float4 w = *reinterpret_cast<const float4*>(&Ws[k + kk][c0]);
#pragma unroll
            for (int i = 0; i < 4; i++) {
                acc[i][0] += ar[i][kk] * w.x;
                acc[i][1] += ar[i][kk] * w.y;
                acc[i][2] += ar[i][kk] * w.z;
                acc[i][3] += ar[i][kk] * w.w;
            }
        }
    }

    if (STATS) {
        if (t < 64) { bs[t] = 0.f; bq[t] = 0.f; }
        __syncthreads();
    }
    float ssum[4] = {0.f, 0.f, 0.f, 0.f}, ssq[4] = {0.f, 0.f, 0.f, 0.f};
#pragma unroll
    for (int i = 0; i < 4; i++) {
        int row = row0 + r0 + i;
        if (row < M) {
            float4 v;
            float* vp = &v.x;
#pragma unroll
            for (int j = 0; j < 4; j++) {
                float x = acc[i][j];
                if (BIAS) x += bias[c0 + j];
                if (RELU) x = fmaxf(x, 0.f);
                vp[j] = x;
                if (STATS) { ssum[j] += x; ssq[j] += x * x; }
            }
            *reinterpret_cast<float4*>(&C[(size_t)row * 64 + c0]) = v;
        }
    }
    if (STATS) {
#pragma unroll
        for (int j = 0; j < 4; j++) {
            atomicAdd(&bs[c0 + j], ssum[j]);
            atomicAdd(&bq[c0 + j], ssq[j]);
        }
        __syncthreads();
        if (t < 64) {
            atomicAdd(&stats[t], bs[t]);
            atomicAdd(&stats[64 + t], bq[t]);
        }
    }
}

// ---------------- edge aggregation ----------------
// one wave = one node; lane = channel. Rows padded to multiple of 8.
// Ping-pong record groups: group g+1's ecw loads overlap group g's gathers.

#define LOADP(P, ebase)                                     \
    _Pragma("unroll") for (int j = 0; j < 4; j++)           \
        P[j] = ecw4[((ebase) >> 1) + j];

#define FMAG(P) {                                                          \
    float h[8];                                                            \
    _Pragma("unroll") for (int j = 0; j < 4; j++) {                        \
        h[2*j]   = *(const float*)(Hb + ((unsigned)P[j].x + lane4));       \
        h[2*j+1] = *(const float*)(Hb + ((unsigned)P[j].z + lane4));       \
    }                                                                      \
    _Pragma("unroll") for (int j = 0; j < 4; j++) {                        \
        acc += h[2*j]   * __int_as_float(P[j].y);                          \
        acc += h[2*j+1] * __int_as_float(P[j].w);                          \
    } }

template<bool RELU>
__global__ __launch_bounds__(256) void agg_kernel(
    const float* __restrict__ H, const int* __restrict__ rowp,
    const int2* __restrict__ ecw,
    const float* __restrict__ dis, const float* __restrict__ bias,
    float* __restrict__ Hout, float* __restrict__ stats, int N)
{
    __shared__ float bs[64], bq[64];
    const int4* ecw4 = (const int4*)ecw;
    int t = threadIdx.x;
    int lane = t & 63;
    unsigned lane4 = (unsigned)lane << 2;
    const char* Hb = (const char*)H;
    int base = (blockIdx.x * 4 + (t >> 6)) * 8;
    float b = bias[lane];
    float ssum = 0.f, ssq = 0.f;
    for (int u = 0; u < 8; u++) {
        int n = base + u;
        if (n >= N) break;
        int e0 = rowp[n], e1 = rowp[n + 1];
        float acc = 0.f;
        int ng = (e1 - e0) >> 3;
        if (ng > 0) {
            int4 pa[4], pb[4];
            int e = e0;
            LOADP(pa, e);
            int rem = ng - 1;
            while (rem >= 2) {
                LOADP(pb, e + 8); FMAG(pa);
                LOADP(pa, e + 16); FMAG(pb);
                e += 16; rem -= 2;
            }
            if (rem == 1) { LOADP(pb, e + 8); FMAG(pa); FMAG(pb); }
            else { FMAG(pa); }
        }
        float dn = dis[n];
        acc += H[(size_t)n * 64 + lane] * (dn * dn);
        acc += b;
        if (RELU) acc = fmaxf(acc, 0.f);
        Hout[(size_t)n * 64 + lane] = acc;
        ssum += acc;
        ssq += acc * acc;
    }
    if (t < 64) { bs[t] = 0.f; bq[t] = 0.f; }
    __syncthreads();
    atomicAdd(&bs[lane], ssum);
    atomicAdd(&bq[lane], ssq);
    __syncthreads();
    if (t < 64) {
        atomicAdd(&stats[t], bs[t]);
        atomicAdd(&stats[64 + t], bq[t]);
    }
}

// ---------------- BN prep: stats -> (scale, shift) ----------------

__global__ void bnprep_kernel(const float* __restrict__ stats, const float* __restrict__ g,
                              const float* __restrict__ b, float* __restrict__ ss, float cntInv) {
    int c = threadIdx.x;
    float mean = stats[c] * cntInv;
    float var = stats[64 + c] * cntInv - mean * mean;
    float sc = g[c] * rsqrtf(var + 1e-5f);
    ss[c] = sc;
    ss[64 + c] = b[c] - mean * sc;
}

// ---------------- pooling (batch sorted -> run-length accumulate) ----------------

__global__ __launch_bounds__(256) void pool_kernel(
    const float* __restrict__ H, const int* __restrict__ batch,
    const float* __restrict__ ss, float* __restrict__ P, int N)
{
    int t = threadIdx.x;
    int lane = t & 63;
    int base = (blockIdx.x * 4 + (t >> 6)) * 8;
    float sc = ss[lane], sh = ss[64 + lane];
    float acc = 0.f;
    int gprev = -1;
    for (int u = 0; u < 8; u++) {
        int n = base + u;
        if (n >= N) break;
        int g = batch[n];
        if (g != gprev) {
            if (gprev >= 0) atomicAdd(&P[(size_t)gprev * 64 + lane], acc);
            acc = 0.f;
            gprev = g;
        }
        acc += H[(size_t)n * 64 + lane] * sc + sh;
    }
    if (gprev >= 0) atomicAdd(&P[(size_t)gprev * 64 + lane], acc);
}

// ---------------- output head ----------------

__global__ __launch_bounds__(256) void final_kernel(
    const float* __restrict__ P, const float* __restrict__ ss,
    const float* __restrict__ outw, const float* __restrict__ outb,
    float* __restrict__ out, int G)
{
    int t = threadIdx.x;
    int lane = t & 63;
    int g = blockIdx.x * 4 + (t >> 6);
    if (g >= G) return;
    float v = (P[(size_t)g * 64 + lane] * ss[lane] + ss[64 + lane]) * outw[lane];
#pragma unroll
    for (int off = 32; off >= 1; off >>= 1) v += __shfl_xor(v, off, 64);
    if (lane == 0) out[g] = v + outb[0];
}

// ---------------- launch ----------------

extern "C" void kernel_launch(void* const* d_in, const int* in_sizes, int n_in,
                              void* d_out, int out_size, void* d_ws, size_t ws_size,
                              hipStream_t stream)
{
    const float* x      = (const float*)d_in[0];
    const int*   ei     = (const int*)d_in[1];
    const int*   batch  = (const int*)d_in[2];
    const float* w1     = (const float*)d_in[3];
    const float* b1     = (const float*)d_in[4];
    const float* bn1_g  = (const float*)d_in[5];
    const float* bn1_b  = (const float*)d_in[6];
    const float* conv_w = (const float*)d_in[7];
    const float* conv_b = (const float*)d_in[8];
    const float* bnc_g  = (const float*)d_in[9];
    const float* bnc_b  = (const float*)d_in[10];
    const float* mlp_w  = (const float*)d_in[11];
    const float* mlp_b  = (const float*)d_in[12];
    const float* bnm_g  = (const float*)d_in[13];
    const float* bnm_b  = (const float*)d_in[14];
    const float* out_w  = (const float*)d_in[15];
    const float* out_b  = (const float*)d_in[16];
    float* out = (float*)d_out;

    const int N = in_sizes[0] / N_FEAT;   // 100000 nodes
    const int E = in_sizes[1] / 2;        // 3.2M edges
    const int G = out_size;               // 4096 graphs
    const int* esrc = ei;
    const int* edst = ei + E;

    char* ws = (char*)d_ws;
    size_t off = 0;
    auto alloc = [&](size_t bytes) {
        size_t cur = off;
        off += (bytes + 255) & ~(size_t)255;
        return (void*)(ws + cur);
    };

    int*   deg   = (int*)alloc((size_t)N * 4);
    float* dis   = (float*)alloc((size_t)N * 4);
    int*   rtmp  = (int*)alloc((size_t)N * 4);
    int*   rowp  = (int*)alloc((size_t)(N + 1) * 4);
    int*   cur   = (int*)alloc((size_t)N * 4);
    int*   blk   = (int*)alloc(256 * 4);
    int2*  ecw   = (int2*)alloc(((size_t)E + 8ull * N) * 8);   // padded CSR
    float* bufA  = (float*)alloc((size_t)(N + 64) * 64 * 4);
    float* bufB  = (float*)alloc((size_t)(N + 64) * 64 * 4);
    float* stats = (float*)alloc(7 * 128 * 4);
    float* ssbuf = (float*)alloc(7 * 128 * 4);
    float* P     = (float*)alloc((size_t)G * 64 * 4);
    float* pA    = (float*)alloc((size_t)G * 64 * 4);
    float* pB    = (float*)alloc((size_t)G * 64 * 4);

    hipMemsetAsync(deg, 0, (size_t)N * 4, stream);
    hipMemsetAsync(stats, 0, 7 * 128 * 4, stream);
    hipMemsetAsync(P, 0, (size_t)G * 64 * 4, stream);

    // graph prep
    hist_kernel<<<(E + 255) / 256, 256, 0, stream>>>(edst, E, deg);
    dis_kernel<<<(N + 255) / 256, 256, 0, stream>>>(deg, dis, N);
    int nchunk = (N + 1023) / 1024;
    scanA_kernel<<<nchunk, 256, 0, stream>>>(deg, N, rtmp, blk);
    scanB_kernel<<<1, 128, 0, stream>>>(blk, nchunk);
    scanC_kernel<<<(N + 255) / 256, 256, 0, stream>>>(rtmp, blk, deg, N, rowp, cur);
    int npx = (N + 7) / 8;
    fill8_kernel<<<NSLICE * 8, 256, 0, stream>>>(esrc, edst, E, dis, cur, ecw, npx);
    pad_kernel<<<(N + 255) / 256, 256, 0, stream>>>(cur, rowp, ecw, N);

    int gemmN_grid = (N + 63) / 64;
    int aggN_grid = (N + 31) / 32;

    // layer 1: x @ w1 -> agg (+b1, relu, stats0)
    gemm_kernel<128, false, false, false, false><<<gemmN_grid, 256, 0, stream>>>(
        x, w1, nullptr, nullptr, nullptr, bufA, nullptr, N);
    agg_kernel<true><<<aggN_grid, 256, 0, stream>>>(
        bufA, rowp, ecw, dis, b1, bufB, stats, N);
    bnprep_kernel<<<1, 64, 0, stream>>>(stats, bn1_g, bn1_b, ssbuf, 1.0f / N);

    // conv layers
    for (int i = 0; i < 3; i++) {
        const float* W  = conv_w + (size_t)i * 64 * 64;
        const float* bb = conv_b + (size_t)i * 64;
        float* st     = stats + (size_t)(1 + i) * 128;
        float* ss_in  = ssbuf + (size_t)i * 128;
        float* ss_out = ssbuf + (size_t)(1 + i) * 128;
        gemm_kernel<64, true, false, false, false><<<gemmN_grid, 256, 0, stream>>>(
            bufB, W, ss_in, ss_in + 64, nullptr, bufA, nullptr, N);
        agg_kernel<false><<<aggN_grid, 256, 0, stream>>>(
            bufA, rowp, ecw, dis, bb, bufB, st, N);
        bnprep_kernel<<<1, 64, 0, stream>>>(st, bnc_g + (size_t)i * 64, bnc_b + (size_t)i * 64,
                                            ss_out, 1.0f / N);
    }

    // pooling (applies conv3 BN)
    pool_kernel<<<aggN_grid, 256, 0, stream>>>(bufB, batch, ssbuf + 3 * 128, P, N);

    // MLP
    int gemmG_grid = (G + 63) / 64;
    gemm_kernel<64, false, true, true, true><<<gemmG_grid, 256, 0, stream>>>(
        P, mlp_w, nullptr, nullptr, mlp_b, pA, stats + 4 * 128, G);
    bnprep_kernel<<<1, 64, 0, stream>>>(stats + 4 * 128, bnm_g, bnm_b, ssbuf + 4 * 128, 1.0f / G);

    gemm_kernel<64, true, true, true, true><<<gemmG_grid, 256, 0, stream>>>(
        pA, mlp_w + 64 * 64, ssbuf + 4 * 128, ssbuf + 4 * 128 + 64,
        mlp_b + 64, pB, stats + 5 * 128, G);
    bnprep_kernel<<<1, 64, 0, stream>>>(stats + 5 * 128, bnm_g + 64, bnm_b + 64, ssbuf + 5 * 128, 1.0f / G);

    gemm_kernel<64, true, true, true, true><<<gemmG_grid, 256, 0, stream>>>(
        pB, mlp_w + 2 * 64 * 64, ssbuf + 5 * 128, ssbuf + 5 * 128 + 64,
        mlp_b + 2 * 64, pA, stats + 6 * 128, G);
    bnprep_kernel<<<1, 64, 0, stream>>>(stats + 6 * 128, bnm_g + 2 * 64, bnm_b + 2 * 64, ssbuf + 6 * 128, 1.0f / G);

    final_kernel<<<(G + 3) / 4, 256, 0, stream>>>(pA, ssbuf + 6 * 128, out_w, out_b, out, G);
}

// Round 8
// 1108.749 us; speedup vs baseline: 1.8557x; 1.0199x over previous
//
#include <hip/hip_runtime.h>
#include <hip/hip_bf16.h>

#define N_FEAT 128
#define DIM 64

// ---------------- graph prep ----------------

__global__ void hist_kernel(const int* __restrict__ dst, int E, int* __restrict__ cnt) {
    int e = blockIdx.x * blockDim.x + threadIdx.x;
    if (e < E) atomicAdd(&cnt[__builtin_nontemporal_load(&dst[e])], 1);
}

__global__ void dis_kernel(const int* __restrict__ cnt, float* __restrict__ dis, int N) {
    int i = blockIdx.x * blockDim.x + threadIdx.x;
    if (i < N) dis[i] = rsqrtf((float)cnt[i] + 1.0f);
}

// pass A: per-block (1024 elems) inclusive scan of PADDED degree (deg rounded up to 8)
__global__ void scanA_kernel(const int* __restrict__ cnt, int N,
                             int* __restrict__ tmp, int* __restrict__ blk) {
    __shared__ int ts[256];
    int t = threadIdx.x;
    int base = blockIdx.x * 1024 + t * 4;
    int v[4];
    int s = 0;
#pragma unroll
    for (int j = 0; j < 4; j++) {
        int i = base + j;
        v[j] = (i < N) ? ((cnt[i] + 7) & ~7) : 0;
        s += v[j];
    }
    ts[t] = s;
    __syncthreads();
    for (int off = 1; off < 256; off <<= 1) {
        int x = (t >= off) ? ts[t - off] : 0;
        __syncthreads();
        ts[t] += x;
        __syncthreads();
    }
    int run = ts[t] - s;
#pragma unroll
    for (int j = 0; j < 4; j++) {
        run += v[j];
        int i = base + j;
        if (i < N) tmp[i] = run;
    }
    if (t == 255) blk[blockIdx.x] = ts[255];
}

// pass B: exclusive scan of block totals (single block)
__global__ void scanB_kernel(int* __restrict__ blk, int nb) {
    __shared__ int ts[128];
    int t = threadIdx.x;
    int v = (t < nb) ? blk[t] : 0;
    ts[t] = v;
    __syncthreads();
    for (int off = 1; off < 128; off <<= 1) {
        int x = (t >= off) ? ts[t - off] : 0;
        __syncthreads();
        ts[t] += x;
        __syncthreads();
    }
    if (t < nb) blk[t] = ts[t] - v;
}

// pass C: final exclusive padded row_ptr + cursor copy
__global__ void scanC_kernel(const int* __restrict__ tmp, const int* __restrict__ blk,
                             const int* __restrict__ cnt,
                             int N, int* __restrict__ rowp, int* __restrict__ cur) {
    int i = blockIdx.x * blockDim.x + threadIdx.x;
    if (i < N) {
        int b = i >> 10;
        int local = i & 1023;
        int excl = blk[b] + (local ? tmp[i - 1] : 0);
        rowp[i] = excl;
        cur[i] = excl;
        if (i == N - 1) rowp[N] = excl + ((cnt[i] + 7) & ~7);
    }
}

// XCD-affine CSR fill, 4B records (src byte-offset only; weight folded into H
// via dis-prescale). Edge-list reads are NON-TEMPORAL so they don't evict the
// partially-filled record lines from the XCD's L2 before they merge.
#define NSLICE 256
__global__ __launch_bounds__(256) void fill8_kernel(
    const int* __restrict__ src, const int* __restrict__ dst, int E,
    int* __restrict__ cur, int* __restrict__ ecwi, int npx) {
    int xcd = blockIdx.x & 7;
    int slice = blockIdx.x >> 3;
    int per = (E + NSLICE - 1) / NSLICE;
    int lo = slice * per;
    int hi = min(lo + per, E);
    int dlo = xcd * npx, dhi = dlo + npx;
    for (int e = lo + threadIdx.x; e < hi; e += 256) {
        int d = __builtin_nontemporal_load(&dst[e]);
        if (d >= dlo && d < dhi) {
            int s = __builtin_nontemporal_load(&src[e]);
            int pos = atomicAdd(&cur[d], 1);
            ecwi[pos] = s << 8;
        }
    }
}

// pad tail of each row with records pointing at the zeroed dummy row N
__global__ void pad_kernel(const int* __restrict__ cur, const int* __restrict__ rowp,
                           int* __restrict__ ecwi, int N) {
    int i = blockIdx.x * blockDim.x + threadIdx.x;
    if (i < N) {
        int p = cur[i], e = rowp[i + 1];
        int dummy = N << 8;
        for (; p < e; p++) ecwi[p] = dummy;
    }
}

// ---------------- GEMM: C[M,64] = f(A[M,K]) @ W[K,64] ----------------
// DISSCALE: multiply output row r by dis[r] (folds GCN edge weight into H)

template<int K, bool AFFINE, bool BIAS, bool RELU, bool STATS, bool DISSCALE>
__global__ __launch_bounds__(256) void gemm_kernel(
    const float* __restrict__ A, const float* __restrict__ W,
    const float* __restrict__ scale, const float* __restrict__ shift,
    const float* __restrict__ bias, const float* __restrict__ dis,
    float* __restrict__ C, float* __restrict__ stats, int M)
{
    __shared__ float As[64][K + 4];   // +4 keeps float4 rows 16B-aligned
    __shared__ float Ws[K][64];
    __shared__ float bs[64], bq[64];
    int t = threadIdx.x;
    int row0 = blockIdx.x * 64;

    for (int q = t; q < K * 16; q += 256) {
        int k = q >> 4, c4 = (q & 15) << 2;
        float4 w = *reinterpret_cast<const float4*>(&W[k * 64 + c4]);
        *reinterpret_cast<float4*>(&Ws[k][c4]) = w;
    }
    for (int q = t; q < 64 * (K / 4); q += 256) {
        int r = q / (K / 4);
        int k4 = (q % (K / 4)) * 4;
        int row = row0 + r;
        float4 a;
        if (row < M) {
            a = *reinterpret_cast<const float4*>(&A[(size_t)row * K + k4]);
            if (AFFINE) {
                a.x = a.x * scale[k4]     + shift[k4];
                a.y = a.y * scale[k4 + 1] + shift[k4 + 1];
                a.z = a.z * scale[k4 + 2] + shift[k4 + 2];
                a.w = a.w * scale[k4 + 3] + shift[k4 + 3];
            }
        } else {
            a = make_float4(0.f, 0.f, 0.f, 0.f);
        }
        *reinterpret_cast<float4*>(&As[r][k4]) = a;
    }
    __syncthreads();

    int ty = t >> 4, tx = t & 15;
    int r0 = ty * 4, c0 = tx * 4;
    float acc[4][4] = {};
#pragma unroll 2
    for (int k = 0; k < K; k += 4) {
        float4 A0 = *reinterpret_cast<const float4*>(&As[r0 + 0][k]);
        float4 A1 = *reinterpret_cast<const float4*>(&As[r0 + 1][k]);
        float4 A2 = *reinterpret_cast<const float4*>(&As[r0 + 2][k]);
        float4 A3 = *reinterpret_cast<const float4*>(&As[r0 + 3][k]);
        float ar[4][4] = {{A0.x, A0.y, A0.z, A0.w}, {A1.x, A1.y, A1.z, A1.w},
                          {A2.x, A2.y, A2.z, A2.w}, {A3.x, A3.y, A3.z, A3.w}};
#pragma unroll
        for (int kk = 0; kk < 4; kk++) {
            float4 w = *reinterpret_cast<const float4*>(&Ws[k + kk][c0]);
#pragma unroll
            for (int i = 0; i < 4; i++) {
                acc[i][0] += ar[i][kk] * w.x;
                acc[i][1] += ar[i][kk] * w.y;
                acc[i][2] += ar[i][kk] * w.z;
                acc[i][3] += ar[i][kk] * w.w;
            }
        }
    }

    if (STATS) {
        if (t < 64) { bs[t] = 0.f; bq[t] = 0.f; }
        __syncthreads();
    }
    float ssum[4] = {0.f, 0.f, 0.f, 0.f}, ssq[4] = {0.f, 0.f, 0.f, 0.f};
#pragma unroll
    for (int i = 0; i < 4; i++) {
        int row = row0 + r0 + i;
        if (row < M) {
            float dsc = DISSCALE ? dis[row] : 1.f;
            float4 v;
            float* vp = &v.x;
#pragma unroll
            for (int j = 0; j < 4; j++) {
                float x = acc[i][j];
                if (DISSCALE) x *= dsc;
                if (BIAS) x += bias[c0 + j];
                if (RELU) x = fmaxf(x, 0.f);
                vp[j] = x;
                if (STATS) { ssum[j] += x; ssq[j] += x * x; }
            }
            *reinterpret_cast<float4*>(&C[(size_t)row * 64 + c0]) = v;
        }
    }
    if (STATS) {
#pragma unroll
        for (int j = 0; j < 4; j++) {
            atomicAdd(&bs[c0 + j], ssum[j]);
            atomicAdd(&bq[c0 + j], ssq[j]);
        }
        __syncthreads();
        if (t < 64) {
            atomicAdd(&stats[t], bs[t]);
            atomicAdd(&stats[64 + t], bq[t]);
        }
    }
}

// ---------------- edge aggregation ----------------
// H is dis-prescaled: out[n] = dis[n]*(sum_e H[src_e] + H[n]) + b.
// 4B records (src byte-offset), rows padded to 8 with dummy-row refs.
// Ping-pong record groups so group g+1's loads overlap group g's gathers.

#define SUM8(Q0, Q1) {                                                     \
    float h0 = *(const float*)(Hb + ((unsigned)Q0.x + lane4));             \
    float h1 = *(const float*)(Hb + ((unsigned)Q0.y + lane4));             \
    float h2 = *(const float*)(Hb + ((unsigned)Q0.z + lane4));             \
    float h3 = *(const float*)(Hb + ((unsigned)Q0.w + lane4));             \
    float h4 = *(const float*)(Hb + ((unsigned)Q1.x + lane4));             \
    float h5 = *(const float*)(Hb + ((unsigned)Q1.y + lane4));             \
    float h6 = *(const float*)(Hb + ((unsigned)Q1.z + lane4));             \
    float h7 = *(const float*)(Hb + ((unsigned)Q1.w + lane4));             \
    acc += ((h0 + h1) + (h2 + h3)) + ((h4 + h5) + (h6 + h7));              \
}

template<bool RELU>
__global__ __launch_bounds__(256) void agg_kernel(
    const float* __restrict__ H, const int* __restrict__ rowp,
    const int* __restrict__ ecwi,
    const float* __restrict__ dis, const float* __restrict__ bias,
    float* __restrict__ Hout, float* __restrict__ stats, int N)
{
    __shared__ float bs[64], bq[64];
    const int4* rec4 = (const int4*)ecwi;
    int t = threadIdx.x;
    int lane = t & 63;
    unsigned lane4 = (unsigned)lane << 2;
    const char* Hb = (const char*)H;
    int base = (blockIdx.x * 4 + (t >> 6)) * 8;
    float b = bias[lane];
    float ssum = 0.f, ssq = 0.f;
    for (int u = 0; u < 8; u++) {
        int n = base + u;
        if (n >= N) break;
        int e0 = rowp[n], e1 = rowp[n + 1];
        float acc = 0.f;
        int ng = (e1 - e0) >> 3;
        if (ng > 0) {
            int g4 = e0 >> 2;
            int4 a0 = rec4[g4], a1 = rec4[g4 + 1];
            int rem = ng - 1;
            while (rem >= 2) {
                int4 b0 = rec4[g4 + 2], b1 = rec4[g4 + 3];
                SUM8(a0, a1);
                a0 = rec4[g4 + 4]; a1 = rec4[g4 + 5];
                SUM8(b0, b1);
                g4 += 4; rem -= 2;
            }
            if (rem == 1) {
                int4 b0 = rec4[g4 + 2], b1 = rec4[g4 + 3];
                SUM8(a0, a1);
                SUM8(b0, b1);
            } else {
                SUM8(a0, a1);
            }
        }
        acc += H[(size_t)n * 64 + lane];        // self term (already dis-scaled)
        acc = acc * dis[n] + b;
        if (RELU) acc = fmaxf(acc, 0.f);
        Hout[(size_t)n * 64 + lane] = acc;
        ssum += acc;
        ssq += acc * acc;
    }
    if (t < 64) { bs[t] = 0.f; bq[t] = 0.f; }
    __syncthreads();
    atomicAdd(&bs[lane], ssum);
    atomicAdd(&bq[lane], ssq);
    __syncthreads();
    if (t < 64) {
        atomicAdd(&stats[t], bs[t]);
        atomicAdd(&stats[64 + t], bq[t]);
    }
}

// ---------------- BN prep: stats -> (scale, shift) ----------------

__global__ void bnprep_kernel(const float* __restrict__ stats, const float* __restrict__ g,
                              const float* __restrict__ b, float* __restrict__ ss, float cntInv) {
    int c = threadIdx.x;
    float mean = stats[c] * cntInv;
    float var = stats[64 + c] * cntInv - mean * mean;
    float sc = g[c] * rsqrtf(var + 1e-5f);
    ss[c] = sc;
    ss[64 + c] = b[c] - mean * sc;
}

// ---------------- pooling (batch sorted -> run-length accumulate) ----------------

__global__ __launch_bounds__(256) void pool_kernel(
    const float* __restrict__ H, const int* __restrict__ batch,
    const float* __restrict__ ss, float* __restrict__ P, int N)
{
    int t = threadIdx.x;
    int lane = t & 63;
    int base = (blockIdx.x * 4 + (t >> 6)) * 8;
    float sc = ss[lane], sh = ss[64 + lane];
    float acc = 0.f;
    int gprev = -1;
    for (int u = 0; u < 8; u++) {
        int n = base + u;
        if (n >= N) break;
        int g = batch[n];
        if (g != gprev) {
            if (gprev >= 0) atomicAdd(&P[(size_t)gprev * 64 + lane], acc);
            acc = 0.f;
            gprev = g;
        }
        acc += H[(size_t)n * 64 + lane] * sc + sh;
    }
    if (gprev >= 0) atomicAdd(&P[(size_t)gprev * 64 + lane], acc);
}

// ---------------- output head ----------------

__global__ __launch_bounds__(256) void final_kernel(
    const float* __restrict__ P, const float* __restrict__ ss,
    const float* __restrict__ outw, const float* __restrict__ outb,
    float* __restrict__ out, int G)
{
    int t = threadIdx.x;
    int lane = t & 63;
    int g = blockIdx.x * 4 + (t >> 6);
    if (g >= G) return;
    float v = (P[(size_t)g * 64 + lane] * ss[lane] + ss[64 + lane]) * outw[lane];
#pragma unroll
    for (int off = 32; off >= 1; off >>= 1) v += __shfl_xor(v, off, 64);
    if (lane == 0) out[g] = v + outb[0];
}

// ---------------- launch ----------------

extern "C" void kernel_launch(void* const* d_in, const int* in_sizes, int n_in,
                              void* d_out, int out_size, void* d_ws, size_t ws_size,
                              hipStream_t stream)
{
    const float* x      = (const float*)d_in[0];
    const int*   ei     = (const int*)d_in[1];
    const int*   batch  = (const int*)d_in[2];
    const float* w1     = (const float*)d_in[3];
    const float* b1     = (const float*)d_in[4];
    const float* bn1_g  = (const float*)d_in[5];
    const float* bn1_b  = (const float*)d_in[6];
    const float* conv_w = (const float*)d_in[7];
    const float* conv_b = (const float*)d_in[8];
    const float* bnc_g  = (const float*)d_in[9];
    const float* bnc_b  = (const float*)d_in[10];
    const float* mlp_w  = (const float*)d_in[11];
    const float* mlp_b  = (const float*)d_in[12];
    const float* bnm_g  = (const float*)d_in[13];
    const float* bnm_b  = (const float*)d_in[14];
    const float* out_w  = (const float*)d_in[15];
    const float* out_b  = (const float*)d_in[16];
    float* out = (float*)d_out;

    const int N = in_sizes[0] / N_FEAT;   // 100000 nodes
    const int E = in_sizes[1] / 2;        // 3.2M edges
    const int G = out_size;               // 4096 graphs
    const int* esrc = ei;
    const int* edst = ei + E;

    char* ws = (char*)d_ws;
    size_t off = 0;
    auto alloc = [&](size_t bytes) {
        size_t cur = off;
        off += (bytes + 255) & ~(size_t)255;
        return (void*)(ws + cur);
    };

    int*   deg   = (int*)alloc((size_t)N * 4);
    float* dis   = (float*)alloc((size_t)N * 4);
    int*   rtmp  = (int*)alloc((size_t)N * 4);
    int*   rowp  = (int*)alloc((size_t)(N + 1) * 4);
    int*   cur   = (int*)alloc((size_t)N * 4);
    int*   blk   = (int*)alloc(256 * 4);
    int*   ecwi  = (int*)alloc(((size_t)E + 8ull * N) * 4);   // padded CSR, 4B records
    float* bufA  = (float*)alloc((size_t)(N + 64) * 64 * 4);
    float* bufB  = (float*)alloc((size_t)(N + 64) * 64 * 4);
    float* stats = (float*)alloc(7 * 128 * 4);
    float* ssbuf = (float*)alloc(7 * 128 * 4);
    float* P     = (float*)alloc((size_t)G * 64 * 4);
    float* pA    = (float*)alloc((size_t)G * 64 * 4);
    float* pB    = (float*)alloc((size_t)G * 64 * 4);

    hipMemsetAsync(deg, 0, (size_t)N * 4, stream);
    hipMemsetAsync(stats, 0, 7 * 128 * 4, stream);
    hipMemsetAsync(P, 0, (size_t)G * 64 * 4, stream);
    hipMemsetAsync(bufA + (size_t)N * 64, 0, 64 * 4, stream);   // dummy row N = 0

    // graph prep
    hist_kernel<<<(E + 255) / 256, 256, 0, stream>>>(edst, E, deg);
    dis_kernel<<<(N + 255) / 256, 256, 0, stream>>>(deg, dis, N);
    int nchunk = (N + 1023) / 1024;
    scanA_kernel<<<nchunk, 256, 0, stream>>>(deg, N, rtmp, blk);
    scanB_kernel<<<1, 128, 0, stream>>>(blk, nchunk);
    scanC_kernel<<<(N + 255) / 256, 256, 0, stream>>>(rtmp, blk, deg, N, rowp, cur);
    int npx = (N + 7) / 8;
    fill8_kernel<<<NSLICE * 8, 256, 0, stream>>>(esrc, edst, E, cur, ecwi, npx);
    pad_kernel<<<(N + 255) / 256, 256, 0, stream>>>(cur, rowp, ecwi, N);

    int gemmN_grid = (N + 63) / 64;
    int aggN_grid = (N + 31) / 32;

    // layer 1: x @ w1 (dis-prescaled) -> agg (+b1, relu, stats0)
    gemm_kernel<128, false, false, false, false, true><<<gemmN_grid, 256, 0, stream>>>(
        x, w1, nullptr, nullptr, nullptr, dis, bufA, nullptr, N);
    agg_kernel<true><<<aggN_grid, 256, 0, stream>>>(
        bufA, rowp, ecwi, dis, b1, bufB, stats, N);
    bnprep_kernel<<<1, 64, 0, stream>>>(stats, bn1_g, bn1_b, ssbuf, 1.0f / N);

    // conv layers
    for (int i = 0; i < 3; i++) {
        const float* W  = conv_w + (size_t)i * 64 * 64;
        const float* bb = conv_b + (size_t)i * 64;
        float* st     = stats + (size_t)(1 + i) * 128;
        float* ss_in  = ssbuf + (size_t)i * 128;
        float* ss_out = ssbuf + (size_t)(1 + i) * 128;
        gemm_kernel<64, true, false, false, false, true><<<gemmN_grid, 256, 0, stream>>>(
            bufB, W, ss_in, ss_in + 64, nullptr, dis, bufA, nullptr, N);
        agg_kernel<false><<<aggN_grid, 256, 0, stream>>>(
            bufA, rowp, ecwi, dis, bb, bufB, st, N);
        bnprep_kernel<<<1, 64, 0, stream>>>(st, bnc_g + (size_t)i * 64, bnc_b + (size_t)i * 64,
                                            ss_out, 1.0f / N);
    }

    // pooling (applies conv3 BN)
    pool_kernel<<<aggN_grid, 256, 0, stream>>>(bufB, batch, ssbuf + 3 * 128, P, N);

    // MLP
    int gemmG_grid = (G + 63) / 64;
    gemm_kernel<64, false, true, true, true, false><<<gemmG_grid, 256, 0, stream>>>(
        P, mlp_w, nullptr, nullptr, mlp_b, nullptr, pA, stats + 4 * 128, G);
    bnprep_kernel<<<1, 64, 0, stream>>>(stats + 4 * 128, bnm_g, bnm_b, ssbuf + 4 * 128, 1.0f / G);

    gemm_kernel<64, true, true, true, true, false><<<gemmG_grid, 256, 0, stream>>>(
        pA, mlp_w + 64 * 64, ssbuf + 4 * 128, ssbuf + 4 * 128 + 64,
        mlp_b + 64, nullptr, pB, stats + 5 * 128, G);
    bnprep_kernel<<<1, 64, 0, stream>>>(stats + 5 * 128, bnm_g + 64, bnm_b + 64, ssbuf + 5 * 128, 1.0f / G);

    gemm_kernel<64, true, true, true, true, false><<<gemmG_grid, 256, 0, stream>>>(
        pB, mlp_w + 2 * 64 * 64, ssbuf + 5 * 128, ssbuf + 5 * 128 + 64,
        mlp_b + 2 * 64, nullptr, pA, stats + 6 * 128, G);
    bnprep_kernel<<<1, 64, 0, stream>>>(stats + 6 * 128, bnm_g + 2 * 64, bnm_b + 2 * 64, ssbuf + 6 * 128, 1.0f / G);

    final_kernel<<<(G + 3) / 4, 256, 0, stream>>>(pA, ssbuf + 6 * 128, out_w, out_b, out, G);
}